// Round 11
// baseline (869.789 us; speedup 1.0000x reference)
//
#include <hip/hip_runtime.h>

#define NN 100000
#define NE 1200000
#define NG 256
#define INC 7
#define HID 64
#define OUTC 10

#define NBKT 782          // ceil(NN/128) buckets of 128 dst nodes
#define BCAP 2048         // per-bucket capacity (mean 1536, max ~1700)
#define BIN_CHUNK 4096    // edges per k_bin block (256 thr)
#define NBIN_BLK ((NE + BIN_CHUNK - 1) / BIN_CHUNK)  // 293
#define EPT (BIN_CHUNK / 256)  // 16

typedef unsigned int uint;
typedef unsigned short ushort;

// ---- bf16 helpers (RNE) ----
__device__ inline uint pk2bf(float a, float b) {
    uint ua = __float_as_uint(a);
    ua = (ua + 0x7fffu + ((ua >> 16) & 1u)) >> 16;
    uint ub = __float_as_uint(b);
    ub = (ub + 0x7fffu + ((ub >> 16) & 1u)) & 0xffff0000u;
    return ua | ub;
}
__device__ inline ushort f2bf(float f) {
    uint u = __float_as_uint(f);
    return (ushort)((u + 0x7fffu + ((u >> 16) & 1u)) >> 16);
}
__device__ inline float lo2f(uint u) { return __uint_as_float(u << 16); }
__device__ inline float hi2f(uint u) { return __uint_as_float(u & 0xffff0000u); }
__device__ inline float b2f(ushort u) { return __uint_as_float(((uint)u) << 16); }

// ---------------- K1: zero init + Wc precompute ----------------

__global__ void k_zero(float* __restrict__ sums, float* __restrict__ cnt,
                       int* __restrict__ bktcur,
                       const float* __restrict__ W2, const float* __restrict__ linW,
                       float* __restrict__ wsWc) {
    int i = blockIdx.x * blockDim.x + threadIdx.x;
    if (i < NG * 16) sums[i] = 0.0f;
    if (i < NG) cnt[i] = 0.0f;
    if (i < NBKT) bktcur[i] = 0;
    if (i < HID * 16) {  // Wc = W2 @ linW (once)
        int k = i >> 4, o = i & 15;
        float acc = 0.0f;
        if (o < OUTC)
            for (int q = 0; q < HID; ++q) acc += W2[k * HID + q] * linW[q * OUTC + o];
        wsWc[i] = acc;
    }
}

// ---------------- K2: bin edges by dst>>7, packed (src<<7)|(dst&127) ----------------

__global__ __launch_bounds__(256) void k_bin(const int* __restrict__ src,
                                             const int* __restrict__ dst,
                                             int* __restrict__ bktcur,
                                             uint* __restrict__ binned) {
    __shared__ int hcnt[NBKT];
    __shared__ int hbase[NBKT];
    int tid = threadIdx.x;
    int e0 = blockIdx.x * BIN_CHUNK;
    int lim = NE - e0; if (lim > BIN_CHUNK) lim = BIN_CHUNK;

    int dr[EPT], sr[EPT];
    for (int b = tid; b < NBKT; b += 256) hcnt[b] = 0;
    __syncthreads();
#pragma unroll
    for (int u = 0; u < EPT; ++u) {
        int i = tid + u * 256;
        bool ok = i < lim;
        dr[u] = ok ? dst[e0 + i] : -1;
        sr[u] = ok ? src[e0 + i] : 0;
        if (ok) atomicAdd(&hcnt[dr[u] >> 7], 1);
    }
    __syncthreads();
    for (int b = tid; b < NBKT; b += 256) {
        int c = hcnt[b];
        hbase[b] = c ? atomicAdd(&bktcur[b], c) : 0;
        hcnt[b] = 0;  // reuse as intra-block rank counter
    }
    __syncthreads();
#pragma unroll
    for (int u = 0; u < EPT; ++u) {
        if (dr[u] >= 0) {
            int b = dr[u] >> 7;
            int r = atomicAdd(&hcnt[b], 1);
            binned[(size_t)b * BCAP + hbase[b] + r] = ((uint)sr[u] << 7) | (dr[u] & 127);
        }
    }
}

// ---------------- K3: per-bucket degree hist -> dis + prep_x ----------------

__global__ __launch_bounds__(256) void k_hist(const uint* __restrict__ binned,
                                              const int* __restrict__ bktcur,
                                              float* __restrict__ dis,
                                              const float* __restrict__ x,
                                              float* __restrict__ xp) {
    __shared__ int hist[128];
    int b = blockIdx.x, tid = threadIdx.x;
    int nbase = b << 7;
    int nnum = NN - nbase; if (nnum > 128) nnum = 128;
    int m = bktcur[b];
    const uint* bp = binned + (size_t)b * BCAP;
    if (tid < 128) hist[tid] = 0;
    __syncthreads();
    for (int i = tid; i < m; i += 256) atomicAdd(&hist[bp[i] & 127], 1);
    __syncthreads();
    if (tid < nnum) dis[nbase + tid] = rsqrtf((float)hist[tid] + 1.0f);
    for (int i = tid; i < (nnum << 3); i += 256) {
        int n = i >> 3, c = i & 7;
        float dv = rsqrtf((float)hist[n] + 1.0f);
        xp[(((size_t)(nbase + n)) << 3) + c] =
            (c < INC) ? dv * x[(size_t)(nbase + n) * INC + c] : 0.0f;
    }
}

// ---------------- K4: agg0 (LDS scatter) -> gemm8 -> gemm_hid, hwpb bf16 ----------

__global__ __launch_bounds__(256) void k_l01(const float* __restrict__ xp,
                                             const uint* __restrict__ binned,
                                             const int* __restrict__ bktcur,
                                             const float* __restrict__ dis,
                                             const float* __restrict__ W0,
                                             const float* __restrict__ b0,
                                             const float* __restrict__ W1,
                                             ushort* __restrict__ hwpb) {
    __shared__ float sW0[INC][HID];     // 1.8 KB
    __shared__ float sW1[HID][HID];     // 16 KB
    __shared__ float acc0[8][132];      // 4.2 KB  [ch][node]
    __shared__ float h0T[HID][132];     // 33.8 KB [ch][node]
    __shared__ float sdis[128];
    __shared__ float sb0[HID];
    int tid = threadIdx.x, b = blockIdx.x;
    int n0 = b << 7;
    int nnum = NN - n0; if (nnum > 128) nnum = 128;
    int m = bktcur[b];
    const uint* bp = binned + (size_t)b * BCAP;

    for (int i = tid; i < INC * HID; i += 256) sW0[i >> 6][i & 63] = W0[i];
    for (int i = tid; i < HID * HID; i += 256) sW1[i >> 6][i & 63] = W1[i];
    for (int i = tid; i < 8 * 132; i += 256) (&acc0[0][0])[i] = 0.0f;
    if (tid < 128) sdis[tid] = (tid < nnum) ? dis[n0 + tid] : 0.0f;
    if (tid < 64) sb0[tid] = b0[tid];
    __syncthreads();
    // --- agg0: edge-parallel, 2 threads/edge (float4 = 4 ch) ---
    {
        int eg = tid >> 1, l = tid & 1;
        int c0 = l * 4;
        for (int e = eg; e < m; e += 128) {
            uint pk = bp[e];
            int srcn = pk >> 7, dl = pk & 127;
            float4 r = ((const float4*)(xp + ((size_t)srcn << 3)))[l];
            atomicAdd(&acc0[c0 + 0][dl], r.x);
            atomicAdd(&acc0[c0 + 1][dl], r.y);
            atomicAdd(&acc0[c0 + 2][dl], r.z);
            atomicAdd(&acc0[c0 + 3][dl], r.w);
        }
    }
    __syncthreads();
    // --- self + dis: aggx[c][dl] = sdis[dl]*(acc0 + xp[self][c]) ---
    for (int i = tid; i < 128 * 8; i += 256) {
        int dl = i >> 3, c = i & 7;
        float self = (dl < nnum) ? xp[(((size_t)(n0 + dl)) << 3) + c] : 0.0f;
        acc0[c][dl] = sdis[dl] * (acc0[c][dl] + self);
    }
    __syncthreads();
    // --- gemm8 (both 64-node halves) -> h0T (relu, transposed) ---
    {
        int tn = tid >> 4, tc = tid & 15;
#pragma unroll
        for (int h = 0; h < 2; ++h) {
            float a[4][4] = {};
#pragma unroll
            for (int k = 0; k < INC; ++k) {
                float4 h4 = *(const float4*)&acc0[k][h * 64 + tn * 4];
                float4 w4 = *(const float4*)&sW0[k][tc * 4];
                float hv[4] = {h4.x, h4.y, h4.z, h4.w};
                float wv[4] = {w4.x, w4.y, w4.z, w4.w};
#pragma unroll
                for (int i = 0; i < 4; ++i)
#pragma unroll
                    for (int j = 0; j < 4; ++j)
                        a[i][j] = fmaf(hv[i], wv[j], a[i][j]);
            }
#pragma unroll
            for (int i = 0; i < 4; ++i)
#pragma unroll
                for (int j = 0; j < 4; ++j)
                    h0T[tc * 4 + j][h * 64 + tn * 4 + i] =
                        fmaxf(a[i][j] + sb0[tc * 4 + j], 0.0f);
        }
    }
    __syncthreads();
    // --- gemm_hid (both halves): epilogue *dis -> bf16 pack -> hwpb ---
    {
        int tn = tid >> 4, tc = tid & 15;
#pragma unroll
        for (int h = 0; h < 2; ++h) {
            float a[4][4] = {};
#pragma unroll 8
            for (int k = 0; k < HID; ++k) {
                float4 h4 = *(const float4*)&h0T[k][h * 64 + tn * 4];
                float4 w4 = *(const float4*)&sW1[k][tc * 4];
                float hv[4] = {h4.x, h4.y, h4.z, h4.w};
                float wv[4] = {w4.x, w4.y, w4.z, w4.w};
#pragma unroll
                for (int i = 0; i < 4; ++i)
#pragma unroll
                    for (int j = 0; j < 4; ++j)
                        a[i][j] = fmaf(hv[i], wv[j], a[i][j]);
            }
#pragma unroll
            for (int i = 0; i < 4; ++i) {
                int dl = h * 64 + tn * 4 + i;
                int gn = n0 + dl;
                if (gn < NN) {
                    float dsc = sdis[dl];
                    uint2 o;
                    o.x = pk2bf(dsc * a[i][0], dsc * a[i][1]);
                    o.y = pk2bf(dsc * a[i][2], dsc * a[i][3]);
                    ((uint2*)(hwpb + ((size_t)gn << 6)))[tc] = o;
                }
            }
        }
    }
}

// ---------------- K5: agg1 (LDS scatter, 64ch bf16) -> gemm_z -> zb ----------------

__global__ __launch_bounds__(256) void k_l2(const ushort* __restrict__ hwpb,
                                            const uint* __restrict__ binned,
                                            const int* __restrict__ bktcur,
                                            const float* __restrict__ dis,
                                            const float* __restrict__ b1,
                                            const float* __restrict__ wsWc,
                                            ushort* __restrict__ zb) {
    __shared__ float acc[HID][132];   // 33.8 KB [ch][node]
    __shared__ float sWc[HID][16];    // 4 KB
    __shared__ float sdis[128];
    __shared__ float sb1[HID];
    int tid = threadIdx.x, b = blockIdx.x;
    int n0 = b << 7;
    int nnum = NN - n0; if (nnum > 128) nnum = 128;
    int m = bktcur[b];
    const uint* bp = binned + (size_t)b * BCAP;

    for (int i = tid; i < HID * 16; i += 256) sWc[i >> 4][i & 15] = wsWc[i];
    for (int i = tid; i < HID * 132; i += 256) (&acc[0][0])[i] = 0.0f;
    if (tid < 128) sdis[tid] = (tid < nnum) ? dis[n0 + tid] : 0.0f;
    if (tid < 64) sb1[tid] = b1[tid];
    __syncthreads();
    // --- agg1: edge-parallel, 8 threads/edge (uint4 = 8 bf16 ch) ---
    {
        int eg = tid >> 3, l = tid & 7;
        int c0 = l * 8;
        for (int e = eg; e < m; e += 32) {
            uint pk = bp[e];
            int srcn = pk >> 7, dl = pk & 127;
            uint4 r = ((const uint4*)(hwpb + ((size_t)srcn << 6)))[l];
            atomicAdd(&acc[c0 + 0][dl], lo2f(r.x));
            atomicAdd(&acc[c0 + 1][dl], hi2f(r.x));
            atomicAdd(&acc[c0 + 2][dl], lo2f(r.y));
            atomicAdd(&acc[c0 + 3][dl], hi2f(r.y));
            atomicAdd(&acc[c0 + 4][dl], lo2f(r.z));
            atomicAdd(&acc[c0 + 5][dl], hi2f(r.z));
            atomicAdd(&acc[c0 + 6][dl], lo2f(r.w));
            atomicAdd(&acc[c0 + 7][dl], hi2f(r.w));
        }
    }
    __syncthreads();
    // --- self + h1 = relu(dis*(sum) + b1), in place ---
    for (int i = tid; i < 128 * HID; i += 256) {
        int dl = i >> 6, c = i & 63;
        float self = (dl < nnum) ? b2f(hwpb[(((size_t)(n0 + dl)) << 6) + c]) : 0.0f;
        acc[c][dl] = fmaxf(sdis[dl] * (acc[c][dl] + self) + sb1[c], 0.0f);
    }
    __syncthreads();
    // --- gemm_z (both halves): zz = dis ⊙ (h1 @ Wc) -> bf16 ---
    {
        int nq = tid >> 4, c = tid & 15;
#pragma unroll
        for (int h = 0; h < 2; ++h) {
            float a4[4] = {};
#pragma unroll 8
            for (int k = 0; k < HID; ++k) {
                float4 h4 = *(const float4*)&acc[k][h * 64 + nq * 4];
                float w = sWc[k][c];
                a4[0] = fmaf(h4.x, w, a4[0]);
                a4[1] = fmaf(h4.y, w, a4[1]);
                a4[2] = fmaf(h4.z, w, a4[2]);
                a4[3] = fmaf(h4.w, w, a4[3]);
            }
#pragma unroll
            for (int i = 0; i < 4; ++i) {
                int dl = h * 64 + nq * 4 + i;
                int gn = n0 + dl;
                if (gn < NN) zb[((size_t)gn << 4) + c] = f2bf(sdis[dl] * a4[i]);
            }
        }
    }
}

// ---------------- K6: agg2 (LDS scatter, 16ch bf16) + mean-pool ----------------

__global__ __launch_bounds__(256) void k_l3(const ushort* __restrict__ zb,
                                            const uint* __restrict__ binned,
                                            const int* __restrict__ bktcur,
                                            const float* __restrict__ dis,
                                            const int* __restrict__ batch,
                                            float* __restrict__ sums,
                                            float* __restrict__ cnt) {
    __shared__ float acc2[16][132];   // 8.4 KB [ch][node]
    __shared__ float lsum[16][16];
    __shared__ int lcnt_[16];
    __shared__ int s_gmin;
    int tid = threadIdx.x, b = blockIdx.x;
    int n0 = b << 7;
    int nnum = NN - n0; if (nnum > 128) nnum = 128;
    int m = bktcur[b];
    const uint* bp = binned + (size_t)b * BCAP;

    for (int i = tid; i < 16 * 132; i += 256) (&acc2[0][0])[i] = 0.0f;
    if (tid < 256) lsum[tid >> 4][tid & 15] = 0.0f;
    if (tid < 16) lcnt_[tid] = 0;
    if (tid == 0) s_gmin = batch[n0];
    __syncthreads();
    // --- agg2: edge-parallel, 2 threads/edge (uint4 = 8 bf16 ch) ---
    {
        int eg = tid >> 1, l = tid & 1;
        int c0 = l * 8;
        for (int e = eg; e < m; e += 128) {
            uint pk = bp[e];
            int srcn = pk >> 7, dl = pk & 127;
            uint4 r = ((const uint4*)(zb + ((size_t)srcn << 4)))[l];
            atomicAdd(&acc2[c0 + 0][dl], lo2f(r.x));
            atomicAdd(&acc2[c0 + 1][dl], hi2f(r.x));
            atomicAdd(&acc2[c0 + 2][dl], lo2f(r.y));
            atomicAdd(&acc2[c0 + 3][dl], hi2f(r.y));
            atomicAdd(&acc2[c0 + 4][dl], lo2f(r.z));
            atomicAdd(&acc2[c0 + 5][dl], hi2f(r.z));
            atomicAdd(&acc2[c0 + 6][dl], lo2f(r.w));
            atomicAdd(&acc2[c0 + 7][dl], hi2f(r.w));
        }
    }
    __syncthreads();
    // --- self + dis, pool into graph slots ---
    for (int i = tid; i < (nnum << 4); i += 256) {
        int dl = i >> 4, c = i & 15;
        int gn = n0 + dl;
        float self = b2f(zb[((size_t)gn << 4) + c]);
        float v = dis[gn] * (acc2[c][dl] + self);
        int g = batch[gn];
        int slot = g - s_gmin;
        if (slot < 16) {
            atomicAdd(&lsum[slot][c], v);
            if (c == 0) atomicAdd(&lcnt_[slot], 1);
        } else {
            atomicAdd(&sums[g * 16 + c], v);
            if (c == 0) atomicAdd(&cnt[g], 1.0f);
        }
    }
    __syncthreads();
    {
        int slot = tid >> 4, c = tid & 15;
        if (tid < 256 && lcnt_[slot] > 0) {
            atomicAdd(&sums[(s_gmin + slot) * 16 + c], lsum[slot][c]);
            if (c == 0) atomicAdd(&cnt[s_gmin + slot], (float)lcnt_[slot]);
        }
    }
}

// ---------------- K7: head ----------------

__global__ void k_final2(const float* __restrict__ sums, const float* __restrict__ cnt,
                         const float* __restrict__ b2, const float* __restrict__ linW,
                         const float* __restrict__ linb, float* __restrict__ out) {
    int t = blockIdx.x * blockDim.x + threadIdx.x;
    if (t < NG * OUTC) {
        int g = t / OUTC, o = t % OUTC;
        float bc = linb[o];
        for (int q = 0; q < HID; ++q) bc += b2[q] * linW[q * OUTC + o];
        out[t] = sums[g * 16 + o] / fmaxf(cnt[g], 1.0f) + bc;
    }
}

// ---------------- launch ----------------

extern "C" void kernel_launch(void* const* d_in, const int* in_sizes, int n_in,
                              void* d_out, int out_size, void* d_ws, size_t ws_size,
                              hipStream_t stream) {
    const float* x     = (const float*)d_in[0];
    const int*   ei    = (const int*)d_in[1];  // [2, NE]
    const int*   src   = ei;
    const int*   dst   = ei + NE;
    const int*   batch = (const int*)d_in[2];
    const float* W0 = (const float*)d_in[3];
    const float* b0 = (const float*)d_in[4];
    const float* W1 = (const float*)d_in[5];
    const float* b1 = (const float*)d_in[6];
    const float* W2 = (const float*)d_in[7];
    const float* b2 = (const float*)d_in[8];
    const float* linW = (const float*)d_in[9];
    const float* linb = (const float*)d_in[10];
    float* out = (float*)d_out;

    char* ws = (char*)d_ws;
    float*  xp     = (float*)ws;    ws += sizeof(float) * NN * 8;
    ushort* hwpb   = (ushort*)ws;   ws += sizeof(ushort) * NN * HID;
    ushort* zb     = (ushort*)ws;   ws += sizeof(ushort) * NN * 16;
    float*  dis    = (float*)ws;    ws += sizeof(float) * NN;
    float*  sums   = (float*)ws;    ws += sizeof(float) * NG * 16;
    float*  cnt    = (float*)ws;    ws += sizeof(float) * NG;
    float*  wsWc   = (float*)ws;    ws += sizeof(float) * HID * 16;
    int*    bktcur = (int*)ws;      ws += sizeof(int) * NBKT;
    uint*   binned = (uint*)ws;     ws += sizeof(uint) * (size_t)NBKT * BCAP;

    const int TB = 256;

    // bin edges into 128-dst buckets + degrees/normalization
    k_zero<<<16, TB, 0, stream>>>(sums, cnt, bktcur, W2, linW, wsWc);
    k_bin<<<NBIN_BLK, TB, 0, stream>>>(src, dst, bktcur, binned);
    k_hist<<<NBKT, TB, 0, stream>>>(binned, bktcur, dis, x, xp);

    // layer 0 agg (LDS scatter) + gemm8 + gemm_hid -> hwpb bf16
    k_l01<<<NBKT, TB, 0, stream>>>(xp, binned, bktcur, dis, W0, b0, W1, hwpb);

    // layer 1 agg (LDS scatter) + gemm_z (folded head) -> zb bf16
    k_l2<<<NBKT, TB, 0, stream>>>(hwpb, binned, bktcur, dis, b1, wsWc, zb);

    // layer 2 agg (LDS scatter) + mean-pool accumulate
    k_l3<<<NBKT, TB, 0, stream>>>(zb, binned, bktcur, dis, batch, sums, cnt);

    // head
    k_final2<<<(NG * OUTC + TB - 1) / TB, TB, 0, stream>>>(sums, cnt, b2, linW, linb, out);
}

// Round 13
// 849.962 us; speedup vs baseline: 1.0233x; 1.0233x over previous
//
#include <hip/hip_runtime.h>

#define NN 100000
#define NE 1200000
#define NG 256
#define INC 7
#define HID 64
#define OUTC 10

#define NBKT 782          // ceil(NN/128) buckets of 128 dst nodes
#define BCAP 2048         // per-bucket capacity (mean 1536, max ~1700)
#define BIN_CHUNK 4096    // edges per k_bin block (256 thr)
#define NBIN_BLK ((NE + BIN_CHUNK - 1) / BIN_CHUNK)  // 293
#define EPT (BIN_CHUNK / 256)  // 16

typedef unsigned int uint;
typedef unsigned short ushort;

// native fp32 atomic (ds_add_f32 / global_atomic_add_f32, no CAS loop)
__device__ inline void atomAddF(float* p, float v) { unsafeAtomicAdd(p, v); }

// ---- bf16 helpers (RNE) ----
__device__ inline uint pk2bf(float a, float b) {
    uint ua = __float_as_uint(a);
    ua = (ua + 0x7fffu + ((ua >> 16) & 1u)) >> 16;
    uint ub = __float_as_uint(b);
    ub = (ub + 0x7fffu + ((ub >> 16) & 1u)) & 0xffff0000u;
    return ua | ub;
}
__device__ inline ushort f2bf(float f) {
    uint u = __float_as_uint(f);
    return (ushort)((u + 0x7fffu + ((u >> 16) & 1u)) >> 16);
}
__device__ inline float lo2f(uint u) { return __uint_as_float(u << 16); }
__device__ inline float hi2f(uint u) { return __uint_as_float(u & 0xffff0000u); }
__device__ inline float b2f(ushort u) { return __uint_as_float(((uint)u) << 16); }

// ---------------- K1: zero init + Wc precompute ----------------

__global__ void k_zero(float* __restrict__ sums, float* __restrict__ cnt,
                       int* __restrict__ bktcur,
                       const float* __restrict__ W2, const float* __restrict__ linW,
                       float* __restrict__ wsWc) {
    int i = blockIdx.x * blockDim.x + threadIdx.x;
    if (i < NG * 16) sums[i] = 0.0f;
    if (i < NG) cnt[i] = 0.0f;
    if (i < NBKT) bktcur[i] = 0;
    if (i < HID * 16) {  // Wc = W2 @ linW (once)
        int k = i >> 4, o = i & 15;
        float acc = 0.0f;
        if (o < OUTC)
            for (int q = 0; q < HID; ++q) acc += W2[k * HID + q] * linW[q * OUTC + o];
        wsWc[i] = acc;
    }
}

// ---------------- K2: bin edges by dst>>7, packed (src<<7)|(dst&127) ----------------

__global__ __launch_bounds__(256) void k_bin(const int* __restrict__ src,
                                             const int* __restrict__ dst,
                                             int* __restrict__ bktcur,
                                             uint* __restrict__ binned) {
    __shared__ int hcnt[NBKT];
    __shared__ int hbase[NBKT];
    int tid = threadIdx.x;
    int e0 = blockIdx.x * BIN_CHUNK;
    int lim = NE - e0; if (lim > BIN_CHUNK) lim = BIN_CHUNK;

    int dr[EPT], sr[EPT];
    for (int b = tid; b < NBKT; b += 256) hcnt[b] = 0;
    __syncthreads();
#pragma unroll
    for (int u = 0; u < EPT; ++u) {
        int i = tid + u * 256;
        bool ok = i < lim;
        dr[u] = ok ? dst[e0 + i] : -1;
        sr[u] = ok ? src[e0 + i] : 0;
        if (ok) atomicAdd(&hcnt[dr[u] >> 7], 1);
    }
    __syncthreads();
    for (int b = tid; b < NBKT; b += 256) {
        int c = hcnt[b];
        hbase[b] = c ? atomicAdd(&bktcur[b], c) : 0;
        hcnt[b] = 0;  // reuse as intra-block rank counter
    }
    __syncthreads();
#pragma unroll
    for (int u = 0; u < EPT; ++u) {
        if (dr[u] >= 0) {
            int b = dr[u] >> 7;
            int r = atomicAdd(&hcnt[b], 1);
            binned[(size_t)b * BCAP + hbase[b] + r] = ((uint)sr[u] << 7) | (dr[u] & 127);
        }
    }
}

// ---------------- K3: per-bucket degree hist -> dis + prep_x ----------------

__global__ __launch_bounds__(256) void k_hist(const uint* __restrict__ binned,
                                              const int* __restrict__ bktcur,
                                              float* __restrict__ dis,
                                              const float* __restrict__ x,
                                              float* __restrict__ xp) {
    __shared__ int hist[128];
    int b = blockIdx.x, tid = threadIdx.x;
    int nbase = b << 7;
    int nnum = NN - nbase; if (nnum > 128) nnum = 128;
    int m = bktcur[b];
    const uint* bp = binned + (size_t)b * BCAP;
    if (tid < 128) hist[tid] = 0;
    __syncthreads();
    for (int i = tid; i < m; i += 256) atomicAdd(&hist[bp[i] & 127], 1);
    __syncthreads();
    if (tid < nnum) dis[nbase + tid] = rsqrtf((float)hist[tid] + 1.0f);
    for (int i = tid; i < (nnum << 3); i += 256) {
        int n = i >> 3, c = i & 7;
        float dv = rsqrtf((float)hist[n] + 1.0f);
        xp[(((size_t)(nbase + n)) << 3) + c] =
            (c < INC) ? dv * x[(size_t)(nbase + n) * INC + c] : 0.0f;
    }
}

// ---------------- K4: agg0 (native LDS atomics) -> gemm8 -> gemm_hid, hwpb bf16 ----

__global__ __launch_bounds__(512) void k_l01(const float* __restrict__ xp,
                                             const uint* __restrict__ binned,
                                             const int* __restrict__ bktcur,
                                             const float* __restrict__ dis,
                                             const float* __restrict__ W0,
                                             const float* __restrict__ b0,
                                             const float* __restrict__ W1,
                                             ushort* __restrict__ hwpb) {
    __shared__ float sW0[INC][HID];     // 1.8 KB
    __shared__ float sW1[HID][HID];     // 16 KB
    __shared__ float acc0[8][132];      // 4.2 KB  [ch][node]
    __shared__ float h0T[HID][132];     // 33.8 KB [ch][node]
    __shared__ float sdis[128];
    __shared__ float sb0[HID];
    int tid = threadIdx.x, b = blockIdx.x;
    int n0 = b << 7;
    int nnum = NN - n0; if (nnum > 128) nnum = 128;
    int m = bktcur[b];
    const uint* bp = binned + (size_t)b * BCAP;

    for (int i = tid; i < INC * HID; i += 512) sW0[i >> 6][i & 63] = W0[i];
    for (int i = tid; i < HID * HID; i += 512) sW1[i >> 6][i & 63] = W1[i];
    for (int i = tid; i < 8 * 132; i += 512) (&acc0[0][0])[i] = 0.0f;
    if (tid < 128) sdis[tid] = (tid < nnum) ? dis[n0 + tid] : 0.0f;
    if (tid < 64) sb0[tid] = b0[tid];
    __syncthreads();
    // --- agg0: edge-parallel, 2 threads/edge (float4 = 4 ch) ---
    {
        int eg = tid >> 1, l = tid & 1;
        int c0 = l * 4;
        for (int e = eg; e < m; e += 256) {
            uint pk = bp[e];
            int srcn = pk >> 7, dl = pk & 127;
            float4 r = ((const float4*)(xp + ((size_t)srcn << 3)))[l];
            atomAddF(&acc0[c0 + 0][dl], r.x);
            atomAddF(&acc0[c0 + 1][dl], r.y);
            atomAddF(&acc0[c0 + 2][dl], r.z);
            atomAddF(&acc0[c0 + 3][dl], r.w);
        }
    }
    __syncthreads();
    // --- self + dis: aggx[c][dl] = sdis[dl]*(acc0 + xp[self][c]) ---
    for (int i = tid; i < 128 * 8; i += 512) {
        int dl = i >> 3, c = i & 7;
        float self = (dl < nnum) ? xp[(((size_t)(n0 + dl)) << 3) + c] : 0.0f;
        acc0[c][dl] = sdis[dl] * (acc0[c][dl] + self);
    }
    __syncthreads();
    // --- gemm8: half h = tid>>8 handled in parallel -> h0T (relu, transposed) ---
    {
        int h = tid >> 8;
        int t2 = tid & 255;
        int tn = t2 >> 4, tc = t2 & 15;
        float a[4][4] = {};
#pragma unroll
        for (int k = 0; k < INC; ++k) {
            float4 h4 = *(const float4*)&acc0[k][h * 64 + tn * 4];
            float4 w4 = *(const float4*)&sW0[k][tc * 4];
            float hv[4] = {h4.x, h4.y, h4.z, h4.w};
            float wv[4] = {w4.x, w4.y, w4.z, w4.w};
#pragma unroll
            for (int i = 0; i < 4; ++i)
#pragma unroll
                for (int j = 0; j < 4; ++j)
                    a[i][j] = fmaf(hv[i], wv[j], a[i][j]);
        }
#pragma unroll
        for (int i = 0; i < 4; ++i)
#pragma unroll
            for (int j = 0; j < 4; ++j)
                h0T[tc * 4 + j][h * 64 + tn * 4 + i] =
                    fmaxf(a[i][j] + sb0[tc * 4 + j], 0.0f);
    }
    __syncthreads();
    // --- gemm_hid (half per thread-half): epilogue *dis -> bf16 pack -> hwpb ---
    {
        int h = tid >> 8;
        int t2 = tid & 255;
        int tn = t2 >> 4, tc = t2 & 15;
        float a[4][4] = {};
#pragma unroll 8
        for (int k = 0; k < HID; ++k) {
            float4 h4 = *(const float4*)&h0T[k][h * 64 + tn * 4];
            float4 w4 = *(const float4*)&sW1[k][tc * 4];
            float hv[4] = {h4.x, h4.y, h4.z, h4.w};
            float wv[4] = {w4.x, w4.y, w4.z, w4.w};
#pragma unroll
            for (int i = 0; i < 4; ++i)
#pragma unroll
                for (int j = 0; j < 4; ++j)
                    a[i][j] = fmaf(hv[i], wv[j], a[i][j]);
        }
#pragma unroll
        for (int i = 0; i < 4; ++i) {
            int dl = h * 64 + tn * 4 + i;
            int gn = n0 + dl;
            if (gn < NN) {
                float dsc = sdis[dl];
                uint2 o;
                o.x = pk2bf(dsc * a[i][0], dsc * a[i][1]);
                o.y = pk2bf(dsc * a[i][2], dsc * a[i][3]);
                ((uint2*)(hwpb + ((size_t)gn << 6)))[tc] = o;
            }
        }
    }
}

// ---------------- K5: agg1 (native LDS atomics, 64ch bf16) -> gemm_z -> zb ---------

__global__ __launch_bounds__(512) void k_l2(const ushort* __restrict__ hwpb,
                                            const uint* __restrict__ binned,
                                            const int* __restrict__ bktcur,
                                            const float* __restrict__ dis,
                                            const float* __restrict__ b1,
                                            const float* __restrict__ wsWc,
                                            ushort* __restrict__ zb) {
    __shared__ float acc[HID][132];   // 33.8 KB [ch][node]
    __shared__ float sWc[HID][16];    // 4 KB
    __shared__ float sdis[128];
    __shared__ float sb1[HID];
    int tid = threadIdx.x, b = blockIdx.x;
    int n0 = b << 7;
    int nnum = NN - n0; if (nnum > 128) nnum = 128;
    int m = bktcur[b];
    const uint* bp = binned + (size_t)b * BCAP;

    for (int i = tid; i < HID * 16; i += 512) sWc[i >> 4][i & 15] = wsWc[i];
    for (int i = tid; i < HID * 132; i += 512) (&acc[0][0])[i] = 0.0f;
    if (tid < 128) sdis[tid] = (tid < nnum) ? dis[n0 + tid] : 0.0f;
    if (tid < 64) sb1[tid] = b1[tid];
    __syncthreads();
    // --- agg1: edge-parallel, 8 threads/edge (uint4 = 8 bf16 ch) ---
    {
        int eg = tid >> 3, l = tid & 7;
        int c0 = l * 8;
        for (int e = eg; e < m; e += 64) {
            uint pk = bp[e];
            int srcn = pk >> 7, dl = pk & 127;
            uint4 r = ((const uint4*)(hwpb + ((size_t)srcn << 6)))[l];
            atomAddF(&acc[c0 + 0][dl], lo2f(r.x));
            atomAddF(&acc[c0 + 1][dl], hi2f(r.x));
            atomAddF(&acc[c0 + 2][dl], lo2f(r.y));
            atomAddF(&acc[c0 + 3][dl], hi2f(r.y));
            atomAddF(&acc[c0 + 4][dl], lo2f(r.z));
            atomAddF(&acc[c0 + 5][dl], hi2f(r.z));
            atomAddF(&acc[c0 + 6][dl], lo2f(r.w));
            atomAddF(&acc[c0 + 7][dl], hi2f(r.w));
        }
    }
    __syncthreads();
    // --- self + h1 = relu(dis*(sum) + b1), in place ---
    for (int i = tid; i < 128 * HID; i += 512) {
        int dl = i >> 6, c = i & 63;
        float self = (dl < nnum) ? b2f(hwpb[(((size_t)(n0 + dl)) << 6) + c]) : 0.0f;
        acc[c][dl] = fmaxf(sdis[dl] * (acc[c][dl] + self) + sb1[c], 0.0f);
    }
    __syncthreads();
    // --- gemm_z (half per thread-half): zz = dis ⊙ (h1 @ Wc) -> bf16 ---
    {
        int h = tid >> 8;
        int t2 = tid & 255;
        int nq = t2 >> 4, c = t2 & 15;
        float a4[4] = {};
#pragma unroll 8
        for (int k = 0; k < HID; ++k) {
            float4 h4 = *(const float4*)&acc[k][h * 64 + nq * 4];
            float w = sWc[k][c];
            a4[0] = fmaf(h4.x, w, a4[0]);
            a4[1] = fmaf(h4.y, w, a4[1]);
            a4[2] = fmaf(h4.z, w, a4[2]);
            a4[3] = fmaf(h4.w, w, a4[3]);
        }
#pragma unroll
        for (int i = 0; i < 4; ++i) {
            int dl = h * 64 + nq * 4 + i;
            int gn = n0 + dl;
            if (gn < NN) zb[((size_t)gn << 4) + c] = f2bf(sdis[dl] * a4[i]);
        }
    }
}

// ---------------- K6: agg2 (native LDS atomics, 16ch bf16) + mean-pool ------------

__global__ __launch_bounds__(256) void k_l3(const ushort* __restrict__ zb,
                                            const uint* __restrict__ binned,
                                            const int* __restrict__ bktcur,
                                            const float* __restrict__ dis,
                                            const int* __restrict__ batch,
                                            float* __restrict__ sums,
                                            float* __restrict__ cnt) {
    __shared__ float acc2[16][132];   // 8.4 KB [ch][node]
    __shared__ float lsum[16][16];
    __shared__ int lcnt_[16];
    __shared__ int s_gmin;
    int tid = threadIdx.x, b = blockIdx.x;
    int n0 = b << 7;
    int nnum = NN - n0; if (nnum > 128) nnum = 128;
    int m = bktcur[b];
    const uint* bp = binned + (size_t)b * BCAP;

    for (int i = tid; i < 16 * 132; i += 256) (&acc2[0][0])[i] = 0.0f;
    if (tid < 256) lsum[tid >> 4][tid & 15] = 0.0f;
    if (tid < 16) lcnt_[tid] = 0;
    if (tid == 0) s_gmin = batch[n0];
    __syncthreads();
    // --- agg2: edge-parallel, 2 threads/edge (uint4 = 8 bf16 ch) ---
    {
        int eg = tid >> 1, l = tid & 1;
        int c0 = l * 8;
        for (int e = eg; e < m; e += 128) {
            uint pk = bp[e];
            int srcn = pk >> 7, dl = pk & 127;
            uint4 r = ((const uint4*)(zb + ((size_t)srcn << 4)))[l];
            atomAddF(&acc2[c0 + 0][dl], lo2f(r.x));
            atomAddF(&acc2[c0 + 1][dl], hi2f(r.x));
            atomAddF(&acc2[c0 + 2][dl], lo2f(r.y));
            atomAddF(&acc2[c0 + 3][dl], hi2f(r.y));
            atomAddF(&acc2[c0 + 4][dl], lo2f(r.z));
            atomAddF(&acc2[c0 + 5][dl], hi2f(r.z));
            atomAddF(&acc2[c0 + 6][dl], lo2f(r.w));
            atomAddF(&acc2[c0 + 7][dl], hi2f(r.w));
        }
    }
    __syncthreads();
    // --- self + dis, pool into graph slots ---
    for (int i = tid; i < (nnum << 4); i += 256) {
        int dl = i >> 4, c = i & 15;
        int gn = n0 + dl;
        float self = b2f(zb[((size_t)gn << 4) + c]);
        float v = dis[gn] * (acc2[c][dl] + self);
        int g = batch[gn];
        int slot = g - s_gmin;
        if (slot < 16) {
            atomAddF(&lsum[slot][c], v);
            if (c == 0) atomicAdd(&lcnt_[slot], 1);
        } else {
            atomAddF(&sums[g * 16 + c], v);
            if (c == 0) atomAddF(&cnt[g], 1.0f);
        }
    }
    __syncthreads();
    {
        int slot = tid >> 4, c = tid & 15;
        if (tid < 256 && lcnt_[slot] > 0) {
            atomAddF(&sums[(s_gmin + slot) * 16 + c], lsum[slot][c]);
            if (c == 0) atomAddF(&cnt[s_gmin + slot], (float)lcnt_[slot]);
        }
    }
}

// ---------------- K7: head ----------------

__global__ void k_final2(const float* __restrict__ sums, const float* __restrict__ cnt,
                         const float* __restrict__ b2, const float* __restrict__ linW,
                         const float* __restrict__ linb, float* __restrict__ out) {
    int t = blockIdx.x * blockDim.x + threadIdx.x;
    if (t < NG * OUTC) {
        int g = t / OUTC, o = t % OUTC;
        float bc = linb[o];
        for (int q = 0; q < HID; ++q) bc += b2[q] * linW[q * OUTC + o];
        out[t] = sums[g * 16 + o] / fmaxf(cnt[g], 1.0f) + bc;
    }
}

// ---------------- launch ----------------

extern "C" void kernel_launch(void* const* d_in, const int* in_sizes, int n_in,
                              void* d_out, int out_size, void* d_ws, size_t ws_size,
                              hipStream_t stream) {
    const float* x     = (const float*)d_in[0];
    const int*   ei    = (const int*)d_in[1];  // [2, NE]
    const int*   src   = ei;
    const int*   dst   = ei + NE;
    const int*   batch = (const int*)d_in[2];
    const float* W0 = (const float*)d_in[3];
    const float* b0 = (const float*)d_in[4];
    const float* W1 = (const float*)d_in[5];
    const float* b1 = (const float*)d_in[6];
    const float* W2 = (const float*)d_in[7];
    const float* b2 = (const float*)d_in[8];
    const float* linW = (const float*)d_in[9];
    const float* linb = (const float*)d_in[10];
    float* out = (float*)d_out;

    char* ws = (char*)d_ws;
    float*  xp     = (float*)ws;    ws += sizeof(float) * NN * 8;
    ushort* hwpb   = (ushort*)ws;   ws += sizeof(ushort) * NN * HID;
    ushort* zb     = (ushort*)ws;   ws += sizeof(ushort) * NN * 16;
    float*  dis    = (float*)ws;    ws += sizeof(float) * NN;
    float*  sums   = (float*)ws;    ws += sizeof(float) * NG * 16;
    float*  cnt    = (float*)ws;    ws += sizeof(float) * NG;
    float*  wsWc   = (float*)ws;    ws += sizeof(float) * HID * 16;
    int*    bktcur = (int*)ws;      ws += sizeof(int) * NBKT;
    uint*   binned = (uint*)ws;     ws += sizeof(uint) * (size_t)NBKT * BCAP;

    const int TB = 256;

    // bin edges into 128-dst buckets + degrees/normalization
    k_zero<<<16, TB, 0, stream>>>(sums, cnt, bktcur, W2, linW, wsWc);
    k_bin<<<NBIN_BLK, TB, 0, stream>>>(src, dst, bktcur, binned);
    k_hist<<<NBKT, TB, 0, stream>>>(binned, bktcur, dis, x, xp);

    // layer 0 agg (native LDS atomics) + gemm8 + gemm_hid -> hwpb bf16
    k_l01<<<NBKT, 512, 0, stream>>>(xp, binned, bktcur, dis, W0, b0, W1, hwpb);

    // layer 1 agg (native LDS atomics) + gemm_z (folded head) -> zb bf16
    k_l2<<<NBKT, 512, 0, stream>>>(hwpb, binned, bktcur, dis, b1, wsWc, zb);

    // layer 2 agg (native LDS atomics) + mean-pool accumulate
    k_l3<<<NBKT, TB, 0, stream>>>(zb, binned, bktcur, dis, batch, sums, cnt);

    // head
    k_final2<<<(NG * OUTC + TB - 1) / TB, TB, 0, stream>>>(sums, cnt, b2, linW, linb, out);
}